// Round 3
// baseline (960.581 us; speedup 1.0000x reference)
//
#include <hip/hip_runtime.h>

#define KD 12288   // rows/cols of adj
#define FIN 500
#define KPAD 512
#define HID 64
#define NOUT 16

typedef __attribute__((ext_vector_type(8))) short bf16x8;
typedef __attribute__((ext_vector_type(4))) float f32x4;

__device__ __forceinline__ unsigned short f2bf(float f) {
  union { float f; unsigned int u; } v; v.f = f;
  unsigned int u = v.u;
  unsigned int r = (u + 0x7fffu + ((u >> 16) & 1u)) >> 16;  // RTN-even
  return (unsigned short)r;
}

__device__ __forceinline__ unsigned long long pack4(float4 v) {
  unsigned int lo = (unsigned int)f2bf(v.x) | ((unsigned int)f2bf(v.y) << 16);
  unsigned int hi = (unsigned int)f2bf(v.z) | ((unsigned int)f2bf(v.w) << 16);
  return (unsigned long long)lo | ((unsigned long long)hi << 32);
}

__device__ __forceinline__ f32x4 mfma16(bf16x8 a, bf16x8 b, f32x4 c) {
  return __builtin_amdgcn_mfma_f32_16x16x32_bf16(a, b, c, 0, 0, 0);
}

// A-tile fragment-ordered LDS layout for a 16-row x 64-k tile of bf16.
// slot(hg, r, i): hg = k/8 (0..7), r = row (0..15), i = k%8. 16B per (hg,r) row.
// byte addr = ((hg*16 + r)*16 + i*2) ^ ((hg&7)<<4)   (XOR kills bank hotspots)
__device__ __forceinline__ int a_slot(int hg, int r, int ibyte) {
  return (((hg << 4) + r) << 4 | ibyte) ^ ((hg & 7) << 4);
}

// ---------------- setup: W1 -> W1T bf16 [64][512] (zero-padded), W2 -> W2T bf16 [16][64]
__global__ void k_setup(const float* __restrict__ W1, const float* __restrict__ W2,
                        unsigned short* __restrict__ W1T, unsigned short* __restrict__ W2T) {
  int flat = blockIdx.x * 256 + threadIdx.x;
  if (flat < HID * KPAD) {
    int c = flat >> 9, k = flat & (KPAD - 1);
    W1T[flat] = (k < FIN) ? f2bf(W1[k * HID + c]) : (unsigned short)0;
  } else {
    int f2 = flat - HID * KPAD;
    if (f2 < NOUT * HID) {
      int c = f2 >> 6, k = f2 & 63;
      W2T[f2] = f2bf(W2[k * NOUT + c]);
    }
  }
}

// ---------------- GEMM1: h1T[c][r] = (x @ W1 + b1)^T  (bf16 out)
__global__ __launch_bounds__(256) void k_g1(const float* __restrict__ x,
                                            const unsigned short* __restrict__ W1T,
                                            const float* __restrict__ b1,
                                            unsigned short* __restrict__ h1T) {
  __shared__ unsigned char Ab[2][2048];
  __shared__ unsigned short tr[64][16];
  const int tid = threadIdx.x;
  const int w = tid >> 6, l = tid & 63;
  const int r0 = blockIdx.x << 4;
  const int sr = tid >> 4, sk4 = (tid & 15) << 2;
  const int shg = sk4 >> 3;
  const int aw = a_slot(shg, sr, (sk4 & 7) << 1);
  const int fr = l & 15, fg = l >> 4;
  const int ar0 = a_slot(fg, fr, 0);
  const int ar1 = a_slot(4 + fg, fr, 0);
  const float* ap = x + (size_t)(r0 + sr) * FIN;
  const unsigned short* bp = W1T + (w * 16 + fr) * KPAD + (fg << 3);
  f32x4 acc = {0.f, 0.f, 0.f, 0.f};
  for (int s = 0; s < KPAD / 64; ++s) {
    int k0 = s * 64 + sk4;
    float4 av = make_float4(0.f, 0.f, 0.f, 0.f);
    if (k0 < FIN) av = *(const float4*)(ap + k0);
    unsigned char* buf = Ab[s & 1];
    *(unsigned long long*)(buf + aw) = pack4(av);
    __syncthreads();
    bf16x8 a0 = *(const bf16x8*)(buf + ar0);
    bf16x8 a1 = *(const bf16x8*)(buf + ar1);
    bf16x8 b0 = *(const bf16x8*)(bp + s * 64);
    bf16x8 b1v = *(const bf16x8*)(bp + s * 64 + 32);
    acc = mfma16(a0, b0, acc);
    acc = mfma16(a1, b1v, acc);
    __syncthreads();
  }
  const int c = w * 16 + fr;
  const float bias = b1[c];
#pragma unroll
  for (int q = 0; q < 4; ++q) tr[c][fg * 4 + q] = f2bf(acc[q] + bias);
  __syncthreads();
  int cc = tid >> 2, rr = (tid & 3) << 2;
  *(unsigned long long*)(h1T + (size_t)cc * KD + r0 + rr) = *(unsigned long long*)&tr[cc][rr];
}

// ---------------- L1: H[r][c] = relu(adj @ h1)   (bf16 out, row-major [12288][64])
__global__ __launch_bounds__(256) void k_l1(const float* __restrict__ adj,
                                            const unsigned short* __restrict__ h1T,
                                            unsigned short* __restrict__ H) {
  __shared__ unsigned char Ab[2][2048];
  const int tid = threadIdx.x;
  const int w = tid >> 6, l = tid & 63;
  const int r0 = blockIdx.x << 4;
  const int sr = tid >> 4, sk4 = (tid & 15) << 2;
  const int shg = sk4 >> 3;
  const int aw = a_slot(shg, sr, (sk4 & 7) << 1);
  const int fr = l & 15, fg = l >> 4;
  const int ar0 = a_slot(fg, fr, 0);
  const int ar1 = a_slot(4 + fg, fr, 0);
  const float* ap = adj + (size_t)(r0 + sr) * KD + sk4;
  const unsigned short* bp = h1T + (size_t)(w * 16 + fr) * KD + (fg << 3);
  f32x4 acc = {0.f, 0.f, 0.f, 0.f};
  float4 av = *(const float4*)ap;                 // step 0 A
  bf16x8 bv0 = *(const bf16x8*)(bp);              // step 0 B
  bf16x8 bv1 = *(const bf16x8*)(bp + 32);
#pragma unroll 2
  for (int s = 0; s < KD / 64; ++s) {
    unsigned char* buf = Ab[s & 1];
    *(unsigned long long*)(buf + aw) = pack4(av);  // stage step s
    int sn = (s < KD / 64 - 1) ? s + 1 : s;
    av = *(const float4*)(ap + (size_t)sn * 64);   // prefetch A(s+1)
    __syncthreads();
    bf16x8 a0 = *(const bf16x8*)(buf + ar0);
    bf16x8 a1 = *(const bf16x8*)(buf + ar1);
    bf16x8 nb0 = *(const bf16x8*)(bp + (size_t)sn * 64);       // prefetch B(s+1)
    bf16x8 nb1 = *(const bf16x8*)(bp + (size_t)sn * 64 + 32);
    acc = mfma16(a0, bv0, acc);
    acc = mfma16(a1, bv1, acc);
    bv0 = nb0; bv1 = nb1;
  }
  const int c = w * 16 + fr;
#pragma unroll
  for (int q = 0; q < 4; ++q) {
    float v = acc[q];
    v = v > 0.f ? v : 0.f;
    H[(size_t)(r0 + fg * 4 + q) * HID + c] = f2bf(v);
  }
}

// ---------------- GEMM2: h2T[c][r] = (H @ W2 + b2)^T  (bf16 out), 1 wave / 16 rows
__global__ __launch_bounds__(64) void k_g2(const unsigned short* __restrict__ Hm,
                                           const unsigned short* __restrict__ W2T,
                                           const float* __restrict__ b2,
                                           unsigned short* __restrict__ h2T) {
  __shared__ unsigned char Ab[2048];
  __shared__ unsigned short tr[16][16];
  const int l = threadIdx.x;
  const int r0 = blockIdx.x << 4;
  const int fr = l & 15, fg = l >> 4;
  const int sr = l >> 2;
#pragma unroll
  for (int j = 0; j < 4; ++j) {
    int k4 = (l & 3) * 16 + j * 4;
    int hg = k4 >> 3;
    unsigned long long v = *(const unsigned long long*)(Hm + (size_t)(r0 + sr) * HID + k4);
    *(unsigned long long*)(Ab + a_slot(hg, sr, (k4 & 7) << 1)) = v;
  }
  __syncthreads();
  bf16x8 a0 = *(const bf16x8*)(Ab + a_slot(fg, fr, 0));
  bf16x8 a1 = *(const bf16x8*)(Ab + a_slot(4 + fg, fr, 0));
  bf16x8 b0 = *(const bf16x8*)(W2T + fr * HID + fg * 8);
  bf16x8 b1v = *(const bf16x8*)(W2T + fr * HID + 32 + fg * 8);
  f32x4 acc = {0.f, 0.f, 0.f, 0.f};
  acc = mfma16(a0, b0, acc);
  acc = mfma16(a1, b1v, acc);
  const float bias = b2[fr];
#pragma unroll
  for (int q = 0; q < 4; ++q) tr[fr][fg * 4 + q] = f2bf(acc[q] + bias);
  __syncthreads();
  int cc = l >> 2, rr = (l & 3) << 2;
  *(unsigned long long*)(h2T + (size_t)cc * KD + r0 + rr) = *(unsigned long long*)&tr[cc][rr];
}

// ---------------- L2: out[r][c] = adj @ h2  (fp32 out), K split across 4 waves
__global__ __launch_bounds__(256) void k_l2(const float* __restrict__ adj,
                                            const unsigned short* __restrict__ h2T,
                                            float* __restrict__ out) {
  __shared__ unsigned char Ab[4][2][2048];
  __shared__ float red[4][16][16];
  const int tid = threadIdx.x;
  const int w = tid >> 6, l = tid & 63;
  const int r0 = blockIdx.x << 4;
  const int kb = w * (KD / 4);
  const int fr = l & 15, fg = l >> 4;
  const int sr = l >> 4, sk4 = (l & 15) << 2;
  const int shg = sk4 >> 3;
  const int ar0 = a_slot(fg, fr, 0);
  const int ar1 = a_slot(4 + fg, fr, 0);
  const float* ap0 = adj + (size_t)(r0 + sr) * KD + kb + sk4;
  const unsigned short* bp = h2T + (size_t)fr * KD + kb + (fg << 3);
  f32x4 acc = {0.f, 0.f, 0.f, 0.f};
  float4 av[4];
#pragma unroll
  for (int j = 0; j < 4; ++j) av[j] = *(const float4*)(ap0 + (size_t)(4 * j) * KD);
  bf16x8 bv0 = *(const bf16x8*)(bp);
  bf16x8 bv1 = *(const bf16x8*)(bp + 32);
  const int NS = (KD / 4) / 64;  // 48
  for (int s = 0; s < NS; ++s) {
    unsigned char* buf = Ab[w][s & 1];
#pragma unroll
    for (int j = 0; j < 4; ++j) {
      int row = sr + 4 * j;
      *(unsigned long long*)(buf + a_slot(shg, row, (sk4 & 7) << 1)) = pack4(av[j]);
    }
    int sn = (s < NS - 1) ? s + 1 : s;
#pragma unroll
    for (int j = 0; j < 4; ++j) av[j] = *(const float4*)(ap0 + (size_t)(4 * j) * KD + sn * 64);
    bf16x8 a0 = *(const bf16x8*)(buf + ar0);   // same-wave dep: compiler waits lgkmcnt
    bf16x8 a1 = *(const bf16x8*)(buf + ar1);
    bf16x8 nb0 = *(const bf16x8*)(bp + sn * 64);
    bf16x8 nb1 = *(const bf16x8*)(bp + sn * 64 + 32);
    acc = mfma16(a0, bv0, acc);
    acc = mfma16(a1, bv1, acc);
    bv0 = nb0; bv1 = nb1;
  }
#pragma unroll
  for (int q = 0; q < 4; ++q) red[w][fg * 4 + q][fr] = acc[q];
  __syncthreads();
  int rr = tid >> 4, cc = tid & 15;
  float sum = red[0][rr][cc] + red[1][rr][cc] + red[2][rr][cc] + red[3][rr][cc];
  out[(size_t)(r0 + rr) * NOUT + cc] = sum;
}

extern "C" void kernel_launch(void* const* d_in, const int* in_sizes, int n_in,
                              void* d_out, int out_size, void* d_ws, size_t ws_size,
                              hipStream_t stream) {
  const float* x   = (const float*)d_in[0];
  const float* adj = (const float*)d_in[1];
  const float* W1  = (const float*)d_in[2];
  const float* b1  = (const float*)d_in[3];
  const float* W2  = (const float*)d_in[4];
  const float* b2  = (const float*)d_in[5];
  float* out = (float*)d_out;
  char* ws = (char*)d_ws;
  // ws layout (bytes): W1T 65536 | W2T 2048 | h1T 1572864 | H 1572864 | h2T 393216
  unsigned short* W1T = (unsigned short*)(ws);
  unsigned short* W2T = (unsigned short*)(ws + 65536);
  unsigned short* h1T = (unsigned short*)(ws + 67584);
  unsigned short* Hm  = (unsigned short*)(ws + 1640448);
  unsigned short* h2T = (unsigned short*)(ws + 3213312);

  hipLaunchKernelGGL(k_setup, dim3(132), dim3(256), 0, stream, W1, W2, W1T, W2T);
  hipLaunchKernelGGL(k_g1, dim3(KD / 16), dim3(256), 0, stream, x, W1T, b1, h1T);
  hipLaunchKernelGGL(k_l1, dim3(KD / 16), dim3(256), 0, stream, adj, h1T, Hm);
  hipLaunchKernelGGL(k_g2, dim3(KD / 16), dim3(64), 0, stream, Hm, W2T, b2, h2T);
  hipLaunchKernelGGL(k_l2, dim3(KD / 16), dim3(256), 0, stream, adj, h2T, out);
}